// Round 12
// baseline (9514.008 us; speedup 1.0000x reference)
//
#include <hip/hip_runtime.h>
#include <cstddef>
#include <cstdint>

// 2-layer LSTM decoder, B=2048, Z=64, H=256, D=8, T=250. fp32 in/out.
//
// R21: producer/consumer wave specialization. R20 (2.74 ms) counters show
// phases still serial: stream 12.7k cyc (port-bound) + VALU 7.9k + MFMA.
// Key dependence fact: L0(t) needs only h0(t-1) (own output), not h1. So
// waves 0-3 (A) run layer 0 for ALL 1024 gate-cols at step t=k; waves 4-7
// (B) run layer 1 at t=k-1, one interval behind. Each SIMD = 1 A + 1 B
// wave -> A's stream stalls are filled by B's VALU and vice versa (TLP
// overlap, no per-wave register growth; acc pairs drop 8->4).
// Sync: ONE WG barrier per interval, no flags (no deadlock possible).
// Buffer algebra (all double-buffered, verified disjoint within interval):
//   A reads H0[(k+1)&1] (wrote at k-1), writes H0[k&1];
//   B reads H0[(k-1)&1]=(k+1)&1 (read-read w/ A, ok), reads H1[k&1],
//     writes H1[(k+1)&1]; h1f: writes [(k+1)&1], reads [k&1].
// Weights repacked per-role (A: 64 tiles/wave = 4 batches x {kc0..3 x g0..3};
// B: 128 = 4 x {kc0..7 x g0..3}), same verified tile interior. Residency
// 8 tiles/wave (64 KB) keeps both streams == 0 mod 8 -> slot = j&7 plain.
// Stream 704 KB/interval. LDS ~150.6 KB.
// Go/no-go: absmax ~0.0022 (index bugs explode it); dur >= 2700 clean =>
// overlap refuted, 2741 is the roofline.

#define BSZ    2048
#define ZDIM   64
#define HDIM   256
#define DDIM   8
#define TSTEPS 250
#define ROWS   16
#define NWG    (BSZ / ROWS)   // 128
#define NTH    512            // 8 waves: 0-3 = A (layer0), 4-7 = B (layer1)
#define G4     1024
#define WSTR   264            // h1f/woutT row stride (shorts)

typedef __attribute__((ext_vector_type(4))) int v4i;

__device__ __forceinline__ unsigned short f2bf(float x) {   // RNE f32->bf16
  union { float f; unsigned u; } v; v.f = x;
  unsigned r = v.u + 0x7fff + ((v.u >> 16) & 1);
  return (unsigned short)(r >> 16);
}
__device__ __forceinline__ float bf2f(unsigned short b) {
  union { unsigned u; float f; } v; v.u = (unsigned)b << 16; return v.f;
}
__device__ __forceinline__ float bfl(unsigned u) {          // low bf16 of u32
  union { unsigned u; float f; } v; v.u = u << 16; return v.f;
}
__device__ __forceinline__ float bfh_(unsigned u) {         // high bf16 of u32
  union { unsigned u; float f; } v; v.u = u & 0xffff0000u; return v.f;
}
__device__ __forceinline__ float fexp2(float x) { return __builtin_amdgcn_exp2f(x); }
__device__ __forceinline__ float frcp(float x)  { return __builtin_amdgcn_rcpf(x); }
__device__ __forceinline__ float sigm(float x)  { return frcp(1.f + fexp2(-1.44269504f * x)); }
__device__ __forceinline__ float tanh_(float x) { return 2.f * frcp(1.f + fexp2(-2.88539008f * x)) - 1.f; }
__device__ __forceinline__ char q8(float x, float s) {
  float v = fminf(fmaxf(x * s, -127.f), 127.f);
  return (char)(int)__builtin_rintf(v);
}
// h*s split into hi + lo/254 (lo in [-127,127] exactly since 0.5*254=127)
__device__ __forceinline__ void q8pair(float h, float s, char* hi, char* lo) {
  float hs = fminf(fmaxf(h * s, -127.f), 127.f);
  float hq = __builtin_rintf(hs);
  *hi = (char)(int)hq;
  *lo = (char)(int)__builtin_rintf((hs - hq) * 254.f);
}

// ---------------- initial state (mapping verified R1-R8) ----------------
__global__ void init_state(const float* __restrict__ z,
                           const float* __restrict__ Wfh, const float* __restrict__ bfh,
                           const float* __restrict__ Wfc, const float* __restrict__ bfc,
                           char* __restrict__ h0h, char* __restrict__ h0l,
                           char* __restrict__ h1h, char* __restrict__ h1l,
                           float* __restrict__ c0s, float* __restrict__ c1s)
{
  int idx = blockIdx.x * 256 + threadIdx.x;
  int b = idx >> 8;
  int j = idx & 255;
  int col = ((b & 1) << 8) | j;
  const float* z0 = z + (size_t)(b >> 1) * ZDIM;
  const float* z1 = z + (size_t)(1024 + (b >> 1)) * ZDIM;
  float h0 = bfh[col], c0v = bfc[col], h1 = bfh[col], c1v = bfc[col];
  for (int k = 0; k < ZDIM; ++k) {
    float wh = Wfh[k * 512 + col];
    float wc = Wfc[k * 512 + col];
    float a = z0[k], bb = z1[k];
    h0  += a * wh;  c0v += a * wc;
    h1  += bb * wh; c1v += bb * wc;
  }
  char hi, lo;
  q8pair(h0, 31.75f, &hi, &lo); h0h[idx] = hi; h0l[idx] = lo;
  q8pair(h1, 31.75f, &hi, &lo); h1h[idx] = hi; h1l[idx] = lo;
  c0s[idx] = c0v; c1s[idx] = c1v;
}

// ---------------- per-output-column scales (unchanged) ----------------
__global__ void col_scales(const float* __restrict__ Whh0,
                           const float* __restrict__ Wih1, const float* __restrict__ Whh1,
                           float* __restrict__ cs0, float* __restrict__ qs0,
                           float* __restrict__ cs1, float* __restrict__ qs1)
{
  int c = blockIdx.x * 256 + threadIdx.x;   // 0..2047
  if (c < 1024) {
    float m = 0.f;
    for (int k = 0; k < 256; ++k) m = fmaxf(m, fabsf(Whh0[(size_t)k * G4 + c]));
    cs0[c] = m * (1.f / 16129.f);
    qs0[c] = 127.f / m;
  } else {
    c -= 1024;
    float m = 0.f;
    for (int k = 0; k < 256; ++k) m = fmaxf(m, fabsf(Whh1[(size_t)k * G4 + c]));
    for (int k = 0; k < 256; ++k) m = fmaxf(m, fabsf(Wih1[(size_t)k * G4 + c]));
    cs1[c] = m * (1.f / 16129.f);
    qs1[c] = 127.f / m;
  }
}

// ---- i8 weight pack: role-split per-wave streams (R21) ----
// pA: A-wave a (0..3) handles h-dims [64a,64a+64): tile T = n*16 + kc*4 + g
//     (n = h-batch 0..3, kc 0..3, g = gate 0..3), 64 tiles/wave.
// pB: B-wave b: tile T = n*32 + kc*4 + g (kc 0..7), 128 tiles/wave.
// Tile interior (verified R8): lane 16B at k = kc*64 + lq*16 + jj,
// col = g*256 + 64*wv + 16*n + l15. L1 k<256 -> Whh1, k>=256 -> Wih1[k-256].
__global__ void pack_i8(const float* __restrict__ Whh0,
                        const float* __restrict__ Wih1, const float* __restrict__ Whh1,
                        const float* __restrict__ qs0, const float* __restrict__ qs1,
                        char* __restrict__ pA, char* __restrict__ pB)
{
  int tt   = blockIdx.x * 4 + (threadIdx.x >> 6);   // 0..767
  int lane = threadIdx.x & 63;
  int l15 = lane & 15, lq = lane >> 4;
  union { char c[16]; uint4 u; } v;
  if (tt < 256) {                                   // pA: a = tt>>6, T = tt&63
    int a = tt >> 6, T = tt & 63;
    int n = T >> 4, kc = (T >> 2) & 3, g = T & 3;
    int col = g * 256 + 64 * a + 16 * n + l15;
    float q = qs0[col];
    for (int jj = 0; jj < 16; ++jj) {
      int k = kc * 64 + lq * 16 + jj;
      v.c[jj] = q8(Whh0[(size_t)k * G4 + col], q);
    }
    *(uint4*)(pA + (size_t)tt * 1024 + lane * 16) = v.u;
  } else {                                          // pB: b = t1>>7, T = t1&127
    int t1 = tt - 256;                              // 0..511
    int b = t1 >> 7, T = t1 & 127;
    int n = T >> 5, kc = (T >> 2) & 7, g = T & 3;
    int col = g * 256 + 64 * b + 16 * n + l15;
    float q = qs1[col];
    for (int jj = 0; jj < 16; ++jj) {
      int k = kc * 64 + lq * 16 + jj;
      float wv = (k < 256) ? Whh1[(size_t)k * G4 + col]
                           : Wih1[(size_t)(k - 256) * G4 + col];
      v.c[jj] = q8(wv, q);
    }
    *(uint4*)(pB + (size_t)t1 * 1024 + lane * 16) = v.u;
  }
}

// ---------------- persistent LSTM kernel (layer-split waves) ----------------
__global__ __launch_bounds__(NTH, 1) void lstm_run(
    const float* __restrict__ target,
    const char* __restrict__ pA, const char* __restrict__ pB,
    const float* __restrict__ bih0, const float* __restrict__ bhh0,
    const float* __restrict__ bih1, const float* __restrict__ bhh1,
    const float* __restrict__ Wih0,
    const float* __restrict__ Wout, const float* __restrict__ bout,
    const char* __restrict__ h0h, const char* __restrict__ h0l,
    const char* __restrict__ h1h, const char* __restrict__ h1l,
    const float* __restrict__ c0s, const float* __restrict__ c1s,
    const float* __restrict__ cs0, const float* __restrict__ cs1,
    float* __restrict__ out)
{
  // [buf*256 + group*16 + m] uint4; group = col-group 0..15, m = batch row
  __shared__ uint4 H0h[512], H0l[512];              // 16 KB h0 planes (dbuf)
  __shared__ uint4 H1h[512], H1l[512];              // 16 KB h1 planes (dbuf)
  __shared__ unsigned short h1f[2][16 * WSTR];      // 16.5 KB bf16 h1 (dbuf)
  __shared__ unsigned short woutT[8 * WSTR];        // 4.1 KB
  __shared__ uint4 wxu[1024];                       // 16 KB Wih0 bf16x8
  __shared__ float2 bs0[1024], bs1[1024];           // 16 KB (bias, cs) tables
  __shared__ float xs[4][128];                      // 2 KB per-A-wave x
  __shared__ uint4 wres[8 * 8 * 64];                // 64 KB resident tiles 0..7
                                                    // total ~150.6 KB
  const int tid  = threadIdx.x;
  const int w    = tid >> 6;
  const int lane = tid & 63;
  const int l15  = lane & 15;
  const int lq   = lane >> 4;
  const int b0   = blockIdx.x * ROWS;
  const bool isA = (w < 4);
  const int rw   = w & 3;                           // role-local wave id
  const int myrow = lq * 4;
  char* H0ch = (char*)H0h; char* H0cl = (char*)H0l;
  char* H1ch = (char*)H1h; char* H1cl = (char*)H1l;

  // ---- one-time staging: h0(-1)->H0[1], h1(-1)->H1[1] ----
  {
    int half = tid >> 8, r8 = tid & 255;
    int g = r8 >> 4, m = r8 & 15;
    const char* sh = half ? h1h : h0h;
    const char* sl = half ? h1l : h0l;
    uint4 vh = *(const uint4*)(sh + (size_t)(b0 + m) * HDIM + g * 16);
    uint4 vl = *(const uint4*)(sl + (size_t)(b0 + m) * HDIM + g * 16);
    if (half) { H1h[256 + g * 16 + m] = vh; H1l[256 + g * 16 + m] = vl; }
    else      { H0h[256 + g * 16 + m] = vh; H0l[256 + g * 16 + m] = vl; }
  }
  for (int i = tid; i < HDIM * DDIM; i += NTH) {
    int k = i >> 3, d = i & 7;
    woutT[d * WSTR + k] = f2bf(Wout[i]);
  }
  for (int i = tid; i < G4; i += NTH) {
    uint4 u;
    u.x = ((unsigned)f2bf(Wih0[1 * G4 + i]) << 16) | f2bf(Wih0[0 * G4 + i]);
    u.y = ((unsigned)f2bf(Wih0[3 * G4 + i]) << 16) | f2bf(Wih0[2 * G4 + i]);
    u.z = ((unsigned)f2bf(Wih0[5 * G4 + i]) << 16) | f2bf(Wih0[4 * G4 + i]);
    u.w = ((unsigned)f2bf(Wih0[7 * G4 + i]) << 16) | f2bf(Wih0[6 * G4 + i]);
    wxu[i] = u;
    bs0[i] = make_float2(bih0[i] + bhh0[i], cs0[i]);
    bs1[i] = make_float2(bih1[i] + bhh1[i], cs1[i]);
  }

  // per-thread cell state: A -> c0, B -> c1 (same registers)
  float cst[4][4];
#pragma unroll
  for (int n = 0; n < 4; ++n)
#pragma unroll
    for (int r = 0; r < 4; ++r) {
      int c = 64 * rw + 16 * n + l15;
      cst[n][r] = (isA ? c0s : c1s)[(size_t)(b0 + myrow + r) * HDIM + c];
    }
  // out-proj mapping (B threads; harmless for A): 16 rows x 8 d x 2-way k
  const int opr = (tid >> 4) & 15, opd = (tid >> 1) & 7, opq = tid & 1;
  const float bo_out = bout[opd];

  // weight stream base (role-specific), lane-offset folded in
  const char* gp = (isA ? pA + (size_t)rw * 65536
                        : pB + (size_t)rw * 131072) + lane * 16;

  // resident tiles 0..7 per wave
#pragma unroll
  for (int j = 0; j < 8; ++j)
    wres[w * 512 + j * 64 + lane] = *(const uint4*)(gp + (size_t)j * 1024);
  // 8-deep ring: prologue tiles 8..15 -> slots 0..7 (slot = j&7)
  v4i breg[8];
#pragma unroll
  for (int s = 0; s < 8; ++s)
    breg[s] = *(const v4i*)(gp + (size_t)(8 + s) * 1024);

  __syncthreads();

#pragma unroll 1
  for (int k = 0; k <= TSTEPS; ++k) {
    if (isA) {
      if (k < TSTEPS) {                            // ======== A: L0, t = k ========
        const int rb = (k + 1) & 1, wb = k & 1;
        const float sc0 = (k <= 1) ? 4.f : 1.f;
        const float wq0 = (k == 0) ? 31.75f : 127.f;

        // stage x(t=k) into xs[rw] (wave-private, same-wave ordering)
        {
          int row = lane >> 2, dd = (lane & 3) * 2;
          float2 xv = make_float2(0.f, 0.f);
          if (k > 0)
            xv = *(const float2*)(target + (size_t)(b0 + row) * (TSTEPS * DDIM)
                                  + (size_t)(k - 1) * DDIM + dd);
          *(float2*)&xs[rw][lane * 2] = xv;
        }

        const v4i zi = {0, 0, 0, 0};
#pragma unroll
        for (int n = 0; n < 4; ++n) {
          v4i acch[4], accl[4];
#pragma unroll
          for (int g = 0; g < 4; ++g) { acch[g] = zi; accl[g] = zi; }
          v4i ah, al;
#pragma unroll
          for (int jj = 0; jj < 16; ++jj) {        // j = n*16+jj; kc=jj>>2; g=jj&3
            const int j = n * 16 + jj, g = jj & 3;
            if (g == 0) {
              int kc = jj >> 2;
              int aidx = rb * 256 + (kc * 4 + lq) * 16 + l15;
              ah = __builtin_bit_cast(v4i, H0h[aidx]);
              al = __builtin_bit_cast(v4i, H0l[aidx]);
            }
            v4i bb = (j < 8) ? __builtin_bit_cast(v4i, wres[w * 512 + j * 64 + lane])
                             : breg[j & 7];
            acch[g] = __builtin_amdgcn_mfma_i32_16x16x64_i8(ah, bb, acch[g], 0, 0, 0);
            accl[g] = __builtin_amdgcn_mfma_i32_16x16x64_i8(al, bb, accl[g], 0, 0, 0);
            if (j >= 8) {
              const int jn = j + 8;                // wrap -> next interval tile 8..
              breg[j & 7] = *(const v4i*)(gp + (size_t)(jn < 64 ? jn : jn - 56) * 1024);
            }
          }
          // ---- cell0, batch n ----
          {
            const int c = 64 * rw + 16 * n + l15;
            float4 xa[4], xb[4];
#pragma unroll
            for (int r = 0; r < 4; ++r) {
              xa[r] = *(const float4*)&xs[rw][(myrow + r) * 8];
              xb[r] = *(const float4*)&xs[rw][(myrow + r) * 8 + 4];
            }
            float gf[4][4];
#pragma unroll
            for (int g = 0; g < 4; ++g) {
              uint4 u = wxu[g * 256 + c];
              float w0 = bfl(u.x), w1 = bfh_(u.x);
              float w2 = bfl(u.y), w3 = bfh_(u.y);
              float w4 = bfl(u.z), w5 = bfh_(u.z);
              float w6 = bfl(u.w), w7 = bfh_(u.w);
              float2 bc = bs0[g * 256 + c];
              float cs = bc.y * sc0;
#pragma unroll
              for (int r = 0; r < 4; ++r)
                gf[g][r] = ((float)acch[g][r] + (float)accl[g][r] * (1.f / 254.f)) * cs
                    + bc.x
                    + xa[r].x * w0 + xa[r].y * w1 + xa[r].z * w2 + xa[r].w * w3
                    + xb[r].x * w4 + xb[r].y * w5 + xb[r].z * w6 + xb[r].w * w7;
            }
#pragma unroll
            for (int r = 0; r < 4; ++r) {
              float iv = sigm(gf[0][r]);
              float fv = sigm(gf[1][r]);
              float gv = tanh_(gf[2][r]);
              float ov = sigm(gf[3][r]);
              cst[n][r] = fv * cst[n][r] + iv * gv;
              char hi, lo;
              q8pair(ov * tanh_(cst[n][r]), wq0, &hi, &lo);
              int off = ((wb * 256 + (4 * rw + n) * 16 + myrow + r) << 4) + l15;
              H0ch[off] = hi; H0cl[off] = lo;
            }
          }
        }
      }
    } else {
      if (k >= 1) {                                // ======== B: L1, t = k-1 ========
        const int h1rb = k & 1, h1wb = (k + 1) & 1;
        const int h0rb = (k - 1) & 1;
        const float sc1 = (k == 1) ? 4.f : 1.f;

        // ---- out-proj(t = k-2) from h1f[k&1] ----
        if (k >= 2) {
          float s_ = 0.f;
#pragma unroll
          for (int i = 0; i < 32; ++i) {
            ushort4 hx = *(const ushort4*)&h1f[h1rb][opr * WSTR + opq * 128 + i * 4];
            ushort4 wv = *(const ushort4*)&woutT[opd * WSTR + opq * 128 + i * 4];
            s_ += bf2f(hx.x) * bf2f(wv.x) + bf2f(hx.y) * bf2f(wv.y)
                + bf2f(hx.z) * bf2f(wv.z) + bf2f(hx.w) * bf2f(wv.w);
          }
          s_ += __shfl_xor(s_, 1);
          if (opq == 0)
            out[(size_t)(b0 + opr) * (TSTEPS * DDIM) + (size_t)(k - 2) * DDIM + opd] =
                s_ + bo_out;
        }

        const v4i zi = {0, 0, 0, 0};
#pragma unroll
        for (int n = 0; n < 4; ++n) {
          v4i acch[4], accl[4];
#pragma unroll
          for (int g = 0; g < 4; ++g) { acch[g] = zi; accl[g] = zi; }
          v4i ah, al;
#pragma unroll
          for (int jj = 0; jj < 32; ++jj) {        // j = n*32+jj; kc=jj>>2; g=jj&3
            const int j = n * 32 + jj, g = jj & 3;
            if (g == 0) {
              int kc = jj >> 2;                    // 0..3 h1, 4..7 h0'
              int aidx = (kc < 4) ? (h1rb * 256 + (kc * 4 + lq) * 16 + l15)
                                  : (h0rb * 256 + ((kc - 4) * 4 + lq) * 16 + l15);
              if (kc < 4) { ah = __builtin_bit_cast(v4i, H1h[aidx]);
                            al = __builtin_bit_cast(v4i, H1l[aidx]); }
              else        { ah = __builtin_bit_cast(v4i, H0h[aidx]);
                            al = __builtin_bit_cast(v4i, H0l[aidx]); }
            }
            v4i bb = (j < 8) ? __builtin_bit_cast(v4i, wres[w * 512 + j * 64 + lane])
                             : breg[j & 7];
            acch[g] = __builtin_amdgcn_mfma_i32_16x16x64_i8(ah, bb, acch[g], 0, 0, 0);
            accl[g] = __builtin_amdgcn_mfma_i32_16x16x64_i8(al, bb, accl[g], 0, 0, 0);
            if (j >= 8) {
              const int jn = j + 8;
              breg[j & 7] = *(const v4i*)(gp + (size_t)(jn < 128 ? jn : jn - 120) * 1024);
            }
          }
          // ---- cell1, batch n ----
          {
            const int c = 64 * rw + 16 * n + l15;
            float2 bci = bs1[0 * 256 + c];
            float2 bcf = bs1[1 * 256 + c];
            float2 bcg = bs1[2 * 256 + c];
            float2 bco = bs1[3 * 256 + c];
#pragma unroll
            for (int r = 0; r < 4; ++r) {
              float di = ((float)acch[0][r] + (float)accl[0][r] * (1.f / 254.f)) * (bci.y * sc1) + bci.x;
              float df = ((float)acch[1][r] + (float)accl[1][r] * (1.f / 254.f)) * (bcf.y * sc1) + bcf.x;
              float dg = ((float)acch[2][r] + (float)accl[2][r] * (1.f / 254.f)) * (bcg.y * sc1) + bcg.x;
              float dv = ((float)acch[3][r] + (float)accl[3][r] * (1.f / 254.f)) * (bco.y * sc1) + bco.x;
              float iv = sigm(di);
              float fv = sigm(df);
              float gv = tanh_(dg);
              float ov = sigm(dv);
              cst[n][r] = fv * cst[n][r] + iv * gv;
              float h = ov * tanh_(cst[n][r]);
              char hi, lo;
              q8pair(h, 127.f, &hi, &lo);
              int off = ((h1wb * 256 + (4 * rw + n) * 16 + myrow + r) << 4) + l15;
              H1ch[off] = hi; H1cl[off] = lo;
              h1f[h1wb][(myrow + r) * WSTR + c] = f2bf(h);
            }
          }
        }
      }
    }
    __syncthreads();   // interval boundary: orders all cross-interval WAR/RAW
  }

  // ---- epilogue: out-proj for t=249 from h1f[(TSTEPS+1)&1] = h1f[1] ----
  if (tid >= 256) {
    float s_ = 0.f;
#pragma unroll
    for (int i = 0; i < 32; ++i) {
      ushort4 hx = *(const ushort4*)&h1f[1][opr * WSTR + opq * 128 + i * 4];
      ushort4 wv = *(const ushort4*)&woutT[opd * WSTR + opq * 128 + i * 4];
      s_ += bf2f(hx.x) * bf2f(wv.x) + bf2f(hx.y) * bf2f(wv.y)
          + bf2f(hx.z) * bf2f(wv.z) + bf2f(hx.w) * bf2f(wv.w);
    }
    s_ += __shfl_xor(s_, 1);
    if (opq == 0)
      out[(size_t)(b0 + opr) * (TSTEPS * DDIM) + (size_t)(TSTEPS - 1) * DDIM + opd] =
          s_ + bo_out;
  }
}

extern "C" void kernel_launch(void* const* d_in, const int* in_sizes, int n_in,
                              void* d_out, int out_size, void* d_ws, size_t ws_size,
                              hipStream_t stream) {
  const float* z    = (const float*)d_in[0];
  const float* tgt  = (const float*)d_in[1];
  const float* Wfh  = (const float*)d_in[2];
  const float* bfh  = (const float*)d_in[3];
  const float* Wfc  = (const float*)d_in[4];
  const float* bfc  = (const float*)d_in[5];
  const float* Wih0 = (const float*)d_in[6];
  const float* Whh0 = (const float*)d_in[7];
  const float* bih0 = (const float*)d_in[8];
  const float* bhh0 = (const float*)d_in[9];
  const float* Wih1 = (const float*)d_in[10];
  const float* Whh1 = (const float*)d_in[11];
  const float* bih1 = (const float*)d_in[12];
  const float* bhh1 = (const float*)d_in[13];
  const float* Wout = (const float*)d_in[14];
  const float* bout = (const float*)d_in[15];

  // ws layout (bytes), total ~7.09 MB
  char* ws = (char*)d_ws;
  char*  pA   = ws;                                  // 262,144
  char*  pB   = ws + 262144;                         // 524,288
  char*  h0h  = ws + 786432;                         // 524,288
  char*  h0l  = ws + 1310720;                        // 524,288
  char*  h1h  = ws + 1835008;                        // 524,288
  char*  h1l  = ws + 2359296;                        // 524,288
  float* c0s  = (float*)(ws + 2883584);              // 2,097,152
  float* c1s  = (float*)(ws + 4980736);              // 2,097,152
  float* cs0  = (float*)(ws + 7077888);              // 4,096
  float* qs0  = (float*)(ws + 7081984);              // 4,096
  float* cs1  = (float*)(ws + 7086080);              // 4,096
  float* qs1  = (float*)(ws + 7090176);              // 4,096

  hipLaunchKernelGGL(init_state, dim3(BSZ * HDIM / 256), dim3(256), 0, stream,
                     z, Wfh, bfh, Wfc, bfc, h0h, h0l, h1h, h1l, c0s, c1s);
  hipLaunchKernelGGL(col_scales, dim3(8), dim3(256), 0, stream,
                     Whh0, Wih1, Whh1, cs0, qs0, cs1, qs1);
  hipLaunchKernelGGL(pack_i8, dim3(192), dim3(256), 0, stream,
                     Whh0, Wih1, Whh1, qs0, qs1, pA, pB);
  hipLaunchKernelGGL(lstm_run, dim3(NWG), dim3(NTH), 0, stream,
                     tgt, pA, pB, bih0, bhh0, bih1, bhh1, Wih0, Wout, bout,
                     h0h, h0l, h1h, h1l, c0s, c1s, cs0, cs1, (float*)d_out);
}

// Round 13
// 4088.622 us; speedup vs baseline: 2.3269x; 2.3269x over previous
//
#include <hip/hip_runtime.h>
#include <cstddef>
#include <cstdint>

// 2-layer LSTM decoder, B=2048, Z=64, H=256, D=8, T=250. fp32 in/out.
//
// R22 = R20 (2.74 ms, best) + the 256-register budget unlocked.
// Diagnosis across R15/R16/R19/R21: every spill happened with VGPR_Count
// pinned at 128 -- the compiler's occupancy heuristic, chosen for 4
// waves/SIMD we can never have (LDS 161 KB -> 1 WG/CU -> 2 waves/SIMD,
// whose HW budget is 256 VGPRs/wave). amdgpu_waves_per_eu(1,2) tells the
// compiler occupancy <= 2 is a given -> it may allocate up to 256.
// Spend the headroom on 16 register-resident L1 tiles (wreg[16] = 64
// VGPRs, loaded once, fully-static consumption at L1 j=0..15):
//   stream 672 -> 544 KB/step (-19% on the port-bound phase).
// Slot algebra unchanged: streamed seq = [L0 12..31, L1 16..63] = 68 == 4
// (mod 8) -> slot(j) = (j+4+O)&7 both phases, O alternating 0/4; wraps:
//   L0 j=24..31 prefetch L1 16..23 -> gp1[jn-16]   (was gp1[jn-32])
//   L1 j=56..63 prefetch next L0 12..19 -> gp0[jn-64+12]  (unchanged)
//   prologue identical (gp0 tiles 12..19 -> slots 0..7).
// Everything else byte-identical R20. LDS ~161.1 KB.
// Go/no-go: VGPR_Count ~192-220 (128 => knob refused, revert R20);
// FETCH ~15-19 MB, WRITE ~17-27 MB; absmax 0.002197 unchanged.

#define BSZ    2048
#define ZDIM   64
#define HDIM   256
#define DDIM   8
#define TSTEPS 250
#define ROWS   16
#define NWG    (BSZ / ROWS)   // 128
#define NTH    512            // 8 waves
#define G4     1024
#define WSTR   264            // h1f/woutT row stride (shorts)

typedef __attribute__((ext_vector_type(4))) int v4i;

struct IcO0 { static constexpr int v = 0; };
struct IcO4 { static constexpr int v = 4; };

__device__ __forceinline__ unsigned short f2bf(float x) {   // RNE f32->bf16
  union { float f; unsigned u; } v; v.f = x;
  unsigned r = v.u + 0x7fff + ((v.u >> 16) & 1);
  return (unsigned short)(r >> 16);
}
__device__ __forceinline__ float bf2f(unsigned short b) {
  union { unsigned u; float f; } v; v.u = (unsigned)b << 16; return v.f;
}
__device__ __forceinline__ float bfl(unsigned u) {          // low bf16 of u32
  union { unsigned u; float f; } v; v.u = u << 16; return v.f;
}
__device__ __forceinline__ float bfh_(unsigned u) {         // high bf16 of u32
  union { unsigned u; float f; } v; v.u = u & 0xffff0000u; return v.f;
}
__device__ __forceinline__ float fexp2(float x) { return __builtin_amdgcn_exp2f(x); }
__device__ __forceinline__ float frcp(float x)  { return __builtin_amdgcn_rcpf(x); }
__device__ __forceinline__ float sigm(float x)  { return frcp(1.f + fexp2(-1.44269504f * x)); }
__device__ __forceinline__ float tanh_(float x) { return 2.f * frcp(1.f + fexp2(-2.88539008f * x)) - 1.f; }
__device__ __forceinline__ char q8(float x, float s) {
  float v = fminf(fmaxf(x * s, -127.f), 127.f);
  return (char)(int)__builtin_rintf(v);
}
// h*s split into hi + lo/254 (lo in [-127,127] exactly since 0.5*254=127)
__device__ __forceinline__ void q8pair(float h, float s, char* hi, char* lo) {
  float hs = fminf(fmaxf(h * s, -127.f), 127.f);
  float hq = __builtin_rintf(hs);
  *hi = (char)(int)hq;
  *lo = (char)(int)__builtin_rintf((hs - hq) * 254.f);
}

// ---------------- initial state (mapping verified R1-R8) ----------------
__global__ void init_state(const float* __restrict__ z,
                           const float* __restrict__ Wfh, const float* __restrict__ bfh,
                           const float* __restrict__ Wfc, const float* __restrict__ bfc,
                           char* __restrict__ h0h, char* __restrict__ h0l,
                           char* __restrict__ h1h, char* __restrict__ h1l,
                           float* __restrict__ c0s, float* __restrict__ c1s)
{
  int idx = blockIdx.x * 256 + threadIdx.x;
  int b = idx >> 8;
  int j = idx & 255;
  int col = ((b & 1) << 8) | j;
  const float* z0 = z + (size_t)(b >> 1) * ZDIM;
  const float* z1 = z + (size_t)(1024 + (b >> 1)) * ZDIM;
  float h0 = bfh[col], c0v = bfc[col], h1 = bfh[col], c1v = bfc[col];
  for (int k = 0; k < ZDIM; ++k) {
    float wh = Wfh[k * 512 + col];
    float wc = Wfc[k * 512 + col];
    float a = z0[k], bb = z1[k];
    h0  += a * wh;  c0v += a * wc;
    h1  += bb * wh; c1v += bb * wc;
  }
  char hi, lo;
  q8pair(h0, 31.75f, &hi, &lo); h0h[idx] = hi; h0l[idx] = lo;
  q8pair(h1, 31.75f, &hi, &lo); h1h[idx] = hi; h1l[idx] = lo;
  c0s[idx] = c0v; c1s[idx] = c1v;
}

// ---------------- per-output-column scales (unchanged) ----------------
__global__ void col_scales(const float* __restrict__ Whh0,
                           const float* __restrict__ Wih1, const float* __restrict__ Whh1,
                           float* __restrict__ cs0, float* __restrict__ qs0,
                           float* __restrict__ cs1, float* __restrict__ qs1)
{
  int c = blockIdx.x * 256 + threadIdx.x;   // 0..2047
  if (c < 1024) {
    float m = 0.f;
    for (int k = 0; k < 256; ++k) m = fmaxf(m, fabsf(Whh0[(size_t)k * G4 + c]));
    cs0[c] = m * (1.f / 16129.f);
    qs0[c] = 127.f / m;
  } else {
    c -= 1024;
    float m = 0.f;
    for (int k = 0; k < 256; ++k) m = fmaxf(m, fabsf(Whh1[(size_t)k * G4 + c]));
    for (int k = 0; k < 256; ++k) m = fmaxf(m, fabsf(Wih1[(size_t)k * G4 + c]));
    cs1[c] = m * (1.f / 16129.f);
    qs1[c] = 127.f / m;
  }
}

// ---- i8 weight pack: per-wave-contiguous linear stream (verified R8) ----
__global__ void pack_i8(const float* __restrict__ Whh0,
                        const float* __restrict__ Wih1, const float* __restrict__ Whh1,
                        const float* __restrict__ qs0, const float* __restrict__ qs1,
                        char* __restrict__ p0, char* __restrict__ p1)
{
  int tt   = blockIdx.x * 4 + (threadIdx.x >> 6);   // 0..767
  int lane = threadIdx.x & 63;
  int l15 = lane & 15, lq = lane >> 4;
  union { char c[16]; uint4 u; } v;
  if (tt < 256) {                                   // layer0: w*4+kc, i
    int w = tt >> 5, kc = (tt >> 3) & 3, i = tt & 7;
    int nt = (i >> 1) * 16 + 2 * w + (i & 1);
    int col = nt * 16 + l15;
    float q = qs0[col];
    for (int j = 0; j < 16; ++j) {
      int k = kc * 64 + lq * 16 + j;
      v.c[j] = q8(Whh0[(size_t)k * G4 + col], q);
    }
    *(uint4*)(p0 + (size_t)tt * 1024 + lane * 16) = v.u;
  } else {                                          // layer1: w*8+kc, i
    int t1 = tt - 256;
    int w = t1 >> 6, kc = (t1 >> 3) & 7, i = t1 & 7;
    int nt = (i >> 1) * 16 + 2 * w + (i & 1);
    int col = nt * 16 + l15;
    float q = qs1[col];
    for (int j = 0; j < 16; ++j) {
      int k = kc * 64 + lq * 16 + j;
      float wv = (k < 256) ? Whh1[(size_t)k * G4 + col]
                           : Wih1[(size_t)(k - 256) * G4 + col];
      v.c[j] = q8(wv, q);
    }
    *(uint4*)(p1 + (size_t)t1 * 1024 + lane * 16) = v.u;
  }
}

// ---------------- persistent LSTM kernel ----------------
__global__ __launch_bounds__(NTH, 1)
__attribute__((amdgpu_waves_per_eu(1, 2)))
void lstm_run(
    const float* __restrict__ target,
    const char* __restrict__ p0, const char* __restrict__ p1,
    const float* __restrict__ bih0, const float* __restrict__ bhh0,
    const float* __restrict__ bih1, const float* __restrict__ bhh1,
    const float* __restrict__ Wih0,            // [8,1024] fp32 -> bf16 LDS table
    const float* __restrict__ Wout, const float* __restrict__ bout,
    const char* __restrict__ h0h, const char* __restrict__ h0l,
    const char* __restrict__ h1h, const char* __restrict__ h1l,
    const float* __restrict__ c0s, const float* __restrict__ c1s,
    const float* __restrict__ cs0, const float* __restrict__ cs1,
    float* __restrict__ out)
{
  // double-buffered activation planes: [buf][32 blk-rows * 16], buf = 512 uint4
  __shared__ uint4 X4h[1024];                      // 16 KB
  __shared__ uint4 X4l[1024];                      // 16 KB
  __shared__ unsigned short h1f[16 * WSTR];        // 8.25 KB bf16 h1 (single buf)
  __shared__ unsigned short woutT[8 * WSTR];       // 4.1 KB bf16
  __shared__ uint4 wxu[1024];                      // 16 KB Wih0 bf16x8 per col
  __shared__ uint4 wres[8 * 12 * 64];              // 96 KB resident L0 tiles 0..11
  __shared__ float x_lds[2][128];                  // 1 KB teacher-forced input
                                                   // total ~161.1 KB
  const int tid  = threadIdx.x;
  const int w    = tid >> 6;
  const int lane = tid & 63;
  const int l15  = lane & 15;
  const int lq   = lane >> 4;
  const int b0   = blockIdx.x * ROWS;
  char* Xch = (char*)X4h;
  char* Xcl = (char*)X4l;

  // ---- one-time staging into buffer 0 ----
  {
    int m = tid & 15, blk = tid >> 4;              // 32 blks x 16 m
    const char* sh = (blk < 16) ? h1h : h0h;
    const char* sl = (blk < 16) ? h1l : h0l;
    int jblk = blk & 15;
    X4h[blk * 16 + m] = *(const uint4*)(sh + (size_t)(b0 + m) * HDIM + jblk * 16);
    X4l[blk * 16 + m] = *(const uint4*)(sl + (size_t)(b0 + m) * HDIM + jblk * 16);
  }
  for (int i = tid; i < HDIM * DDIM; i += NTH) {
    int k = i >> 3, d = i & 7;
    woutT[d * WSTR + k] = f2bf(Wout[i]);
  }
  for (int i = tid; i < G4; i += NTH) {            // packed bf16 pairs d={0..7}
    uint4 u;
    u.x = ((unsigned)f2bf(Wih0[1 * G4 + i]) << 16) | f2bf(Wih0[0 * G4 + i]);
    u.y = ((unsigned)f2bf(Wih0[3 * G4 + i]) << 16) | f2bf(Wih0[2 * G4 + i]);
    u.z = ((unsigned)f2bf(Wih0[5 * G4 + i]) << 16) | f2bf(Wih0[4 * G4 + i]);
    u.w = ((unsigned)f2bf(Wih0[7 * G4 + i]) << 16) | f2bf(Wih0[6 * G4 + i]);
    wxu[i] = u;
  }
  if (tid < 128) x_lds[0][tid] = 0.f;              // x(0) = zeros

  const int myrow = lq * 4;
  const int jc0   = 32 * w + l15;
  float c0r[2][4], c1r[2][4];
  float bA0[8], bA1[8], csA0[8], csA1[8];          // flat [g*2+cc]
#pragma unroll
  for (int i = 0; i < 8; ++i) {
    int col = (i >> 1) * 256 + jc0 + 16 * (i & 1);
    bA0[i]  = bih0[col] + bhh0[col];
    bA1[i]  = bih1[col] + bhh1[col];
    csA0[i] = cs0[col];
    csA1[i] = cs1[col];
  }
#pragma unroll
  for (int cc = 0; cc < 2; ++cc) {
    int j = jc0 + cc * 16;
#pragma unroll
    for (int r = 0; r < 4; ++r) {
      c0r[cc][r] = c0s[(size_t)(b0 + myrow + r) * HDIM + j];
      c1r[cc][r] = c1s[(size_t)(b0 + myrow + r) * HDIM + j];
    }
  }
  const int opr = tid >> 5, opd = (tid >> 2) & 7, opq = tid & 3;
  const float bo_out = bout[opd];

  // per-lane weight stream bases; tile j at base + j*1024 (linear)
  const char* gp0 = p0 + (size_t)w * 32768 + lane * 16;
  const char* gp1 = p1 + (size_t)w * 65536 + lane * 16;

  // ---- resident L0 tiles 0..11 (per wave, LDS), loaded once ----
#pragma unroll
  for (int j = 0; j < 12; ++j)
    wres[w * 768 + j * 64 + lane] = *(const uint4*)(gp0 + (size_t)j * 1024);

  // ---- register-resident L1 tiles 0..15 (64 VGPRs), loaded once ----
  v4i wreg[16];
#pragma unroll
  for (int s = 0; s < 16; ++s)
    wreg[s] = *(const v4i*)(gp1 + (size_t)s * 1024);

  // 8-deep stream; prologue (O=0): L0 tile 12+s -> slot (12+s+4)&7 = s
  v4i breg[8];
#pragma unroll
  for (int s = 0; s < 8; ++s)
    breg[s] = *(const v4i*)(gp0 + (size_t)(12 + s) * 1024);

  __syncthreads();

  // ---- one LSTM step; O = stream slot offset (0 or 4), compile-time ----
  auto step = [&](int t, auto tag) __attribute__((always_inline)) {
    constexpr int O = decltype(tag)::v;
    const int xc = (t & 1) << 9;                   // uint4-index base of X_cur
    const int xn = xc ^ 512;                       // X_next

    const float sc0 = (t <= 1) ? 4.f : 1.f;
    const float sc1 = (t == 0) ? 4.f : 1.f;
    const float wq0 = (t == 0) ? 31.75f : 127.f;

    v4i acch[8], accl[8];
    const v4i zi = {0, 0, 0, 0};

    // ============ layer 0: h0 @ Whh0 ============
#pragma unroll
    for (int i = 0; i < 8; ++i) { acch[i] = zi; accl[i] = zi; }
    {
      v4i ah, al;
      {                                            // kc=0 A-fragment
        int aidx = xc + (16 + lq) * 16 + l15;
        ah = __builtin_bit_cast(v4i, X4h[aidx]);
        al = __builtin_bit_cast(v4i, X4l[aidx]);
      }
      // resident tiles 0..11 from LDS: 2-slot rotation (static idx)
      {
        v4i rb[2];
        rb[0] = __builtin_bit_cast(v4i, wres[w * 768 + lane]);
#pragma unroll
        for (int j = 0; j < 12; ++j) {
          if (j == 8) {                            // kc=1 A-fragment
            int aidx = xc + (16 + 4 + lq) * 16 + l15;
            ah = __builtin_bit_cast(v4i, X4h[aidx]);
            al = __builtin_bit_cast(v4i, X4l[aidx]);
          }
          if (j < 11)
            rb[(j + 1) & 1] = __builtin_bit_cast(v4i, wres[w * 768 + (j + 1) * 64 + lane]);
          v4i bb = rb[j & 1];
          const int i = j & 7;
          acch[i] = __builtin_amdgcn_mfma_i32_16x16x64_i8(ah, bb, acch[i], 0, 0, 0);
          accl[i] = __builtin_amdgcn_mfma_i32_16x16x64_i8(al, bb, accl[i], 0, 0, 0);
        }
      }
      // streamed tiles 12..31 (slot = (j+4+O)&7); kc=1 frag current at j=12
#pragma unroll
      for (int j = 12; j < 32; ++j) {
        const int i = j & 7, s = (j + 4 + O) & 7;
        if (i == 0) {                              // j=16,24: kc=2,3
          int kc = j >> 3;
          int aidx = xc + (16 + kc * 4 + lq) * 16 + l15;
          ah = __builtin_bit_cast(v4i, X4h[aidx]);
          al = __builtin_bit_cast(v4i, X4l[aidx]);
        }
        v4i bb = breg[s];
        acch[i] = __builtin_amdgcn_mfma_i32_16x16x64_i8(ah, bb, acch[i], 0, 0, 0);
        accl[i] = __builtin_amdgcn_mfma_i32_16x16x64_i8(al, bb, accl[i], 0, 0, 0);
        const int jn = j + 8;                      // 20..39
        // wrap: L1 streamed tiles start at 16 (0..15 register-resident)
        breg[s] = (jn < 32) ? *(const v4i*)(gp0 + (size_t)jn * 1024)
                            : *(const v4i*)(gp1 + (size_t)(jn - 16) * 1024);
      }
    }

    // ---- deferred out-projection for step t-1 (pre-B reads, post-B writes) ----
    if (t > 0) {
      float s_ = 0.f;
#pragma unroll
      for (int i = 0; i < 16; ++i) {
        ushort4 hx = *(const ushort4*)&h1f[opr * WSTR + i * 16 + opq * 4];
        ushort4 wv = *(const ushort4*)&woutT[opd * WSTR + i * 16 + opq * 4];
        s_ += bf2f(hx.x) * bf2f(wv.x) + bf2f(hx.y) * bf2f(wv.y)
            + bf2f(hx.z) * bf2f(wv.z) + bf2f(hx.w) * bf2f(wv.w);
      }
      s_ += __shfl_xor(s_, 1);
      s_ += __shfl_xor(s_, 2);
      if (opq == 0)
        out[(size_t)(b0 + opr) * (TSTEPS * DDIM) + (size_t)(t - 1) * DDIM + opd] =
            s_ + bo_out;
    }

    // ---- cell 0: dequant + bf16 x-path (x from LDS); h0(t) -> X_next ----
    {
      float4 xa[4], xb[4];
#pragma unroll
      for (int r = 0; r < 4; ++r) {
        xa[r] = *(const float4*)&x_lds[t & 1][(myrow + r) * 8];
        xb[r] = *(const float4*)&x_lds[t & 1][(myrow + r) * 8 + 4];
      }
#pragma unroll
      for (int cc = 0; cc < 2; ++cc) {
        float gf4[4][4];
#pragma unroll
        for (int g = 0; g < 4; ++g) {
          int i = g * 2 + cc;
          int col = g * 256 + jc0 + cc * 16;
          uint4 u = wxu[col];
          float w0 = bfl(u.x), w1 = bfh_(u.x);
          float w2 = bfl(u.y), w3 = bfh_(u.y);
          float w4 = bfl(u.z), w5 = bfh_(u.z);
          float w6 = bfl(u.w), w7 = bfh_(u.w);
          float cs = csA0[i] * sc0;
#pragma unroll
          for (int r = 0; r < 4; ++r)
            gf4[g][r] = ((float)acch[i][r] + (float)accl[i][r] * (1.f / 254.f)) * cs + bA0[i]
                + xa[r].x * w0 + xa[r].y * w1 + xa[r].z * w2 + xa[r].w * w3
                + xb[r].x * w4 + xb[r].y * w5 + xb[r].z * w6 + xb[r].w * w7;
        }
#pragma unroll
        for (int r = 0; r < 4; ++r) {
          float iv = sigm(gf4[0][r]);
          float fv = sigm(gf4[1][r]);
          float gv = tanh_(gf4[2][r]);
          float ov = sigm(gf4[3][r]);
          c0r[cc][r] = fv * c0r[cc][r] + iv * gv;
          char hi, lo;
          q8pair(ov * tanh_(c0r[cc][r]), wq0, &hi, &lo);
          int off = (xn + (16 + 2 * w + cc) * 16 + myrow + r) * 16 + l15;
          Xch[off] = hi; Xcl[off] = lo;
        }
      }
    }
    __syncthreads();   // (B) h0(t) visible; L1 streamed tiles 16..23 landed

    // ---- stage x(t+1) = target[:, t] into buf (t+1)&1 (published by F) ----
    if (tid < 128) {
      int m = tid >> 3, d = tid & 7;
      x_lds[(t + 1) & 1][tid] =
          target[(size_t)(b0 + m) * (TSTEPS * DDIM) + (size_t)t * DDIM + d];
    }

    // ====== layer 1: [h1(t-1) | h0(t)] @ W1 ======
#pragma unroll
    for (int i = 0; i < 8; ++i) { acch[i] = zi; accl[i] = zi; }
    {
      v4i ah, al;
      // register-resident tiles 0..15 (kc = 0,1 -> h1, current buffer)
#pragma unroll
      for (int j = 0; j < 16; ++j) {
        const int i = j & 7;
        if (i == 0) {
          int kc = j >> 3;
          int aidx = xc + (kc * 4 + lq) * 16 + l15;
          ah = __builtin_bit_cast(v4i, X4h[aidx]);
          al = __builtin_bit_cast(v4i, X4l[aidx]);
        }
        acch[i] = __builtin_amdgcn_mfma_i32_16x16x64_i8(ah, wreg[j], acch[i], 0, 0, 0);
        accl[i] = __builtin_amdgcn_mfma_i32_16x16x64_i8(al, wreg[j], accl[i], 0, 0, 0);
      }
      // streamed tiles 16..63 (slot = (j+4+O)&7)
#pragma unroll 8
      for (int j = 16; j < 64; ++j) {
        const int i = j & 7, s = (j + 4 + O) & 7;
        if (i == 0) {
          int kc = j >> 3;                         // 2,3 h1 (cur); 4..7 h0' (next)
          int aidx = (kc < 4) ? (xc + (kc * 4 + lq) * 16 + l15)
                              : (xn + (16 + (kc - 4) * 4 + lq) * 16 + l15);
          ah = __builtin_bit_cast(v4i, X4h[aidx]);
          al = __builtin_bit_cast(v4i, X4l[aidx]);
        }
        acch[i] = __builtin_amdgcn_mfma_i32_16x16x64_i8(ah, breg[s], acch[i], 0, 0, 0);
        accl[i] = __builtin_amdgcn_mfma_i32_16x16x64_i8(al, breg[s], accl[i], 0, 0, 0);
        const int jn = j + 8;
        // wrap: next-step L0 streamed tiles start at 12 (0..11 LDS-resident)
        breg[s] = (jn < 64) ? *(const v4i*)(gp1 + (size_t)jn * 1024)
                            : *(const v4i*)(gp0 + (size_t)(jn - 64 + 12) * 1024);
      }
    }

    // ---- cell 1: writes h1(t) into X_next + bf16 h1f ----
#pragma unroll
    for (int cc = 0; cc < 2; ++cc)
#pragma unroll
      for (int r = 0; r < 4; ++r) {
        float di = ((float)acch[0 + cc][r] + (float)accl[0 + cc][r] * (1.f / 254.f));
        float df = ((float)acch[2 + cc][r] + (float)accl[2 + cc][r] * (1.f / 254.f));
        float dg = ((float)acch[4 + cc][r] + (float)accl[4 + cc][r] * (1.f / 254.f));
        float dv = ((float)acch[6 + cc][r] + (float)accl[6 + cc][r] * (1.f / 254.f));
        float iv = sigm(di * csA1[0 + cc] * sc1 + bA1[0 + cc]);
        float fv = sigm(df * csA1[2 + cc] * sc1 + bA1[2 + cc]);
        float gv = tanh_(dg * csA1[4 + cc] * sc1 + bA1[4 + cc]);
        float ov = sigm(dv * csA1[6 + cc] * sc1 + bA1[6 + cc]);
        c1r[cc][r] = fv * c1r[cc][r] + iv * gv;
        float h = ov * tanh_(c1r[cc][r]);
        char hi, lo;
        q8pair(h, 127.f, &hi, &lo);
        int off = (xn + (2 * w + cc) * 16 + myrow + r) * 16 + l15;
        Xch[off] = hi; Xcl[off] = lo;
        h1f[(myrow + r) * WSTR + jc0 + cc * 16] = f2bf(h);
      }
    __syncthreads();   // (F) h1(t)/h1f/x(t+1) visible; next L0 tiles landed
  };

#pragma unroll 1
  for (int t2 = 0; t2 < TSTEPS; t2 += 2) {
    step(t2,     IcO0{});
    step(t2 + 1, IcO4{});
  }

  // ---- epilogue: out-projection for the final step ----
  {
    float s_ = 0.f;
#pragma unroll
    for (int i = 0; i < 16; ++i) {
      ushort4 hx = *(const ushort4*)&h1f[opr * WSTR + i * 16 + opq * 4];
      ushort4 wv = *(const ushort4*)&woutT[opd * WSTR + i * 16 + opq * 4];
      s_ += bf2f(hx.x) * bf2f(wv.x) + bf2f(hx.y) * bf2f(wv.y)
          + bf2f(hx.z) * bf2f(wv.z) + bf2f(hx.w) * bf2f(wv.w);
    }
    s_ += __shfl_xor(s_, 1);
    s_ += __shfl_xor(s_, 2);
    if (opq == 0)
      out[(size_t)(b0 + opr) * (TSTEPS * DDIM) + (size_t)(TSTEPS - 1) * DDIM + opd] =
          s_ + bo_out;
  }
}

extern "C" void kernel_launch(void* const* d_in, const int* in_sizes, int n_in,
                              void* d_out, int out_size, void* d_ws, size_t ws_size,
                              hipStream_t stream) {
  const float* z    = (const float*)d_in[0];
  const float* tgt  = (const float*)d_in[1];
  const float* Wfh  = (const float*)d_in[2];
  const float* bfh  = (const float*)d_in[3];
  const float* Wfc  = (const float*)d_in[4];
  const float* bfc  = (const float*)d_in[5];
  const float* Wih0 = (const float*)d_in[6];
  const float* Whh0 = (const float*)d_in[7];
  const float* bih0 = (const float*)d_in[8];
  const float* bhh0 = (const float*)d_in[9];
  const float* Wih1 = (const float*)d_in[10];
  const float* Whh1 = (const float*)d_in[11];
  const float* bih1 = (const float*)d_in[12];
  const float* bhh1 = (const float*)d_in[13];
  const float* Wout = (const float*)d_in[14];
  const float* bout = (const float*)d_in[15];

  // ws layout (bytes), total ~7.09 MB
  char* ws = (char*)d_ws;
  char*  p0   = ws;                                  // 262,144
  char*  p1   = ws + 262144;                         // 524,288
  char*  h0h  = ws + 786432;                         // 524,288
  char*  h0l  = ws + 1310720;                        // 524,288
  char*  h1h  = ws + 1835008;                        // 524,288
  char*  h1l  = ws + 2359296;                        // 524,288
  float* c0s  = (float*)(ws + 2883584);              // 2,097,152
  float* c1s  = (float*)(ws + 4980736);              // 2,097,152
  float* cs0  = (float*)(ws + 7077888);              // 4,096
  float* qs0  = (float*)(ws + 7081984);              // 4,096
  float* cs1  = (float*)(ws + 7086080);              // 4,096
  float* qs1  = (float*)(ws + 7090176);              // 4,096

  hipLaunchKernelGGL(init_state, dim3(BSZ * HDIM / 256), dim3(256), 0, stream,
                     z, Wfh, bfh, Wfc, bfc, h0h, h0l, h1h, h1l, c0s, c1s);
  hipLaunchKernelGGL(col_scales, dim3(8), dim3(256), 0, stream,
                     Whh0, Wih1, Whh1, cs0, qs0, cs1, qs1);
  hipLaunchKernelGGL(pack_i8, dim3(192), dim3(256), 0, stream,
                     Whh0, Wih1, Whh1, qs0, qs1, p0, p1);
  hipLaunchKernelGGL(lstm_run, dim3(NWG), dim3(NTH), 0, stream,
                     tgt, p0, p1, bih0, bhh0, bih1, bhh1, Wih0, Wout, bout,
                     h0h, h0l, h1h, h1l, c0s, c1s, cs0, cs1, (float*)d_out);
}